// Round 16
// baseline (117.526 us; speedup 1.0000x reference)
//
#include <hip/hip_runtime.h>
#include <math.h>

#define NB 16
#define IMH 288
#define IMW 384
#define NPIX (IMH*IMW)
#define TPB 256
#define PPT 8
#define BPB (NPIX/(TPB*PPT))   // 54 blocks per batch
#define NBLK (NB*BPB)          // 864
#define NITER 5

// ws doubles: pose[NITER+1][NB][16] (R[9]+t[3], padded to one 128B line)
//           | acc[NITER][NB][27] ; then ints cnt[NITER*NB]
#define PSTRIDE 16
#define POSE_OFF 0
#define ACC_OFF ((NITER+1)*NB*PSTRIDE)
#define WS_DOUBLES (ACC_OFF + NITER*NB*27)

// f32 register-resident LM update (same math/precision as R10's per-wave solve);
// reads acc (27 f64) + pose_in, writes pose_out (f64). One thread. Fully unrolled.
__device__ __forceinline__ void solve_updatef(const double* __restrict__ acc,
                                              const double* __restrict__ pin,
                                              double* __restrict__ pout) {
    float A[6][6], rhs[6], inv[6];
    {
        int k = 0;
        #pragma unroll
        for (int f = 0; f < 6; f++) {
            #pragma unroll 6
            for (int g = f; g < 6; g++) {
                float v = (float)acc[k];
                A[f][g] = v; A[g][f] = v; k++;
            }
        }
    }
    #pragma unroll
    for (int f = 0; f < 6; f++) rhs[f] = -(float)acc[21 + f];

    float tr = A[0][0]+A[1][1]+A[2][2]+A[3][3]+A[4][4]+A[5][5];
    float damp = 1e-4f * tr * (1.0f/6.0f) + 1e-6f;
    #pragma unroll
    for (int f = 0; f < 6; f++) A[f][f] += damp;

    #pragma unroll
    for (int j = 0; j < 6; j++) {
        float s = A[j][j];
        #pragma unroll 6
        for (int m = 0; m < j; m++) s = fmaf(-A[j][m], A[j][m], s);
        float dd = __builtin_amdgcn_sqrtf(fmaxf(s, 1e-20f));
        A[j][j] = dd;
        inv[j] = __builtin_amdgcn_rcpf(dd);
        #pragma unroll 6
        for (int i = j + 1; i < 6; i++) {
            float s2 = A[i][j];
            #pragma unroll 6
            for (int m = 0; m < j; m++) s2 = fmaf(-A[i][m], A[j][m], s2);
            A[i][j] = s2 * inv[j];
        }
    }
    #pragma unroll
    for (int i = 0; i < 6; i++) {
        float s = rhs[i];
        #pragma unroll 6
        for (int m = 0; m < i; m++) s = fmaf(-A[i][m], rhs[m], s);
        rhs[i] = s * inv[i];
    }
    #pragma unroll
    for (int i = 5; i >= 0; i--) {
        float s = rhs[i];
        #pragma unroll 6
        for (int m = i + 1; m < 6; m++) s = fmaf(-A[m][i], rhs[m], s);
        rhs[i] = s * inv[i];
    }

    pout[9]  = pin[9]  + (double)rhs[0];
    pout[10] = pin[10] + (double)rhs[1];
    pout[11] = pin[11] + (double)rhs[2];

    float wx = rhs[3], wy = rhs[4], wz = rhs[5];
    float th = fmaxf(__builtin_amdgcn_sqrtf(fmaf(wx,wx,fmaf(wy,wy,wz*wz))), 1e-8f);
    float ith = __builtin_amdgcn_rcpf(th);
    float kx = wx*ith, ky = wy*ith, kz = wz*ith;
    float st, ctf;
    sincosf(th, &st, &ctf);
    float ct = 1.0f - ctf;
    float E[9];
    E[0] = 1.0f + ct*(kx*kx - 1.0f);
    E[1] = -st*kz + ct*kx*ky;
    E[2] =  st*ky + ct*kx*kz;
    E[3] =  st*kz + ct*ky*kx;
    E[4] = 1.0f + ct*(ky*ky - 1.0f);
    E[5] = -st*kx + ct*ky*kz;
    E[6] = -st*ky + ct*kz*kx;
    E[7] =  st*kx + ct*kz*ky;
    E[8] = 1.0f + ct*(kz*kz - 1.0f);

    float Rin[9];
    #pragma unroll
    for (int i = 0; i < 9; i++) Rin[i] = (float)pin[i];
    #pragma unroll
    for (int i = 0; i < 3; i++) {
        #pragma unroll
        for (int j = 0; j < 3; j++)
            pout[i*3+j] = (double)(E[i*3+0]*Rin[0*3+j] + E[i*3+1]*Rin[1*3+j] + E[i*3+2]*Rin[2*3+j]);
    }
}

__global__ void init_k(double* ws) {
    int i = threadIdx.x;
    for (int k = i; k < WS_DOUBLES; k += TPB) ws[k] = 0.0;
    int* cnt = (int*)(ws + WS_DOUBLES);
    for (int k = i; k < NITER * NB; k += TPB) cnt[k] = 0;
    __syncthreads();
    if (i < NB) {
        double* p = ws + POSE_OFF + i * PSTRIDE;   // pose[0] = identity
        p[0] = 1.0; p[4] = 1.0; p[8] = 1.0;
    }
}

__global__ __launch_bounds__(TPB) void reduce_k(const float* __restrict__ x3d,
                                                const float* __restrict__ conf,
                                                const float* __restrict__ Kmat,
                                                double* __restrict__ ws, int it) {
    const int b = blockIdx.x / BPB;
    const int chunk = blockIdx.x % BPB;
    const int tid = threadIdx.x;

    // ---- issue point loads first; pose loads pipeline behind them ----
    const int ft = chunk * TPB + tid;              // [0, 13824)
    const float4* P4 = reinterpret_cast<const float4*>(x3d + (size_t)b * NPIX * 3) + (size_t)ft * 6;
    const float4* W4 = reinterpret_cast<const float4*>(conf + (size_t)b * NPIX) + (size_t)ft * 2;
    const float4 va = P4[0], vb = P4[1], vc = P4[2], vd = P4[3], ve = P4[4], vf = P4[5];
    const float4 w0 = W4[0], w1 = W4[1];

    // ---- pose: plain loads of the slot published by previous dispatch's tail ----
    const double* pin = ws + POSE_OFF + ((size_t)it * NB + b) * PSTRIDE;
    float R[9], t[3];
    #pragma unroll
    for (int i = 0; i < 9; i++) R[i] = (float)pin[i];
    t[0] = (float)pin[9]; t[1] = (float)pin[10]; t[2] = (float)pin[11];

    __shared__ double lds[TPB / 64][27];

    const float fx = Kmat[b*9 + 0];
    const float fy = Kmat[b*9 + 4];
    const float cx = Kmat[b*9 + 2];
    const float cy = Kmat[b*9 + 5];
    const float delta = (float)(0.1 * sqrt(((double)(IMW*IMW - 1) + (double)(IMH*IMH - 1)) / 12.0));

    const int n0 = ft * PPT;
    const int v0 = n0 / IMW;                       // 8 points share one pixel row
    const float cyv  = cy - (float)v0;
    const float cxu0 = cx - (float)(n0 - v0 * IMW);

    float ppx[8] = { va.x, va.w, vb.z, vc.y, vd.x, vd.w, ve.z, vf.y };
    float ppy[8] = { va.y, vb.x, vb.w, vc.z, vd.y, ve.x, ve.w, vf.z };
    float ppz[8] = { va.z, vb.y, vc.x, vc.w, vd.z, ve.y, vf.x, vf.w };
    float pw[8]  = { w0.x, w0.y, w0.z, w0.w, w1.x, w1.y, w1.z, w1.w };

    float facc[27];
    #pragma unroll
    for (int i = 0; i < 27; i++) facc[i] = 0.0f;

    #pragma unroll
    for (int g = 0; g < PPT; ++g) {
        float px = ppx[g], py = ppy[g], pz = ppz[g], w = pw[g];
        float u_off = cxu0 - (float)g;

        float Xx = fmaf(R[0], px, fmaf(R[1], py, fmaf(R[2], pz, t[0])));
        float Xy = fmaf(R[3], px, fmaf(R[4], py, fmaf(R[5], pz, t[1])));
        float Xz = fmaf(R[6], px, fmaf(R[7], py, fmaf(R[8], pz, t[2])));
        float z  = fmaxf(Xz, 0.01f);
        float iz = __builtin_amdgcn_rcpf(z);

        float Xxiz = Xx * iz, Xyiz = Xy * iz;
        float rx = fmaf(fx, Xxiz, u_off);
        float ry = fmaf(fy, Xyiz, cyv);

        float wrx = w * rx, wry = w * ry;
        float q  = fmaf(wrx, wrx, wry * wry);
        float rs = __builtin_amdgcn_rsqf(fmaxf(q, 1e-16f));
        float rob2 = fminf(1.0f, delta * rs);
        float sq = w * __builtin_amdgcn_sqrtf(rob2);

        float sqiz = sq * iz;
        float a  = fx * sqiz;
        float c  = fy * sqiz;
        float bb = -a * Xxiz;
        float d  = -c * Xyiz;

        float j0[6] = { a, 0.0f, bb,  bb*Xy,               fmaf(a, Xz, -bb*Xx), -a*Xy };
        float j1[6] = { 0.0f, c,  d,  fmaf(d, Xy, -c*Xz), -d*Xx,                 c*Xx };
        float rxs = sq * rx, rys = sq * ry;

        int k = 0;
        #pragma unroll
        for (int f = 0; f < 6; ++f) {
            #pragma unroll
            for (int gg = f; gg < 6; ++gg) {
                facc[k] += j0[f]*j0[gg] + j1[f]*j1[gg];
                k++;
            }
        }
        #pragma unroll
        for (int f = 0; f < 6; ++f)
            facc[21 + f] += j0[f]*rxs + j1[f]*rys;
    }

    // f32 wave reduce (pairwise), f64 from wave partials on
    int lane = tid & 63;
    int wave = tid >> 6;
    #pragma unroll
    for (int i = 0; i < 27; i++) {
        float v = facc[i];
        for (int off = 32; off > 0; off >>= 1) v += __shfl_down(v, off, 64);
        if (lane == 0) lds[wave][i] = (double)v;
    }
    __syncthreads();

    double* acc = ws + ACC_OFF + ((size_t)it * NB + b) * 27;
    if (tid < 27) {
        double v = 0.0;
        #pragma unroll
        for (int wv = 0; wv < TPB/64; wv++) v += lds[wv][tid];
        atomicAdd(acc + tid, v);
    }
    __syncthreads();   // barrier drains vmcnt: block's atomics globally performed

    // ---- tail: last-arriving block per batch solves and publishes pose[it+1] ----
    if (tid == 0) {
        int* cnt = (int*)(ws + WS_DOUBLES);
        int old = atomicAdd(&cnt[it * NB + b], 1);
        if (old == BPB - 1) {
            __threadfence();               // acquire all blocks' acc adds
            double* pout = ws + POSE_OFF + ((size_t)(it+1) * NB + b) * PSTRIDE;
            solve_updatef(acc, pin, pout); // plain stores; kernel boundary publishes
        }
    }
}

__global__ __launch_bounds__(64) void loss_k(const double* __restrict__ ws,
                                             const float* __restrict__ pose,
                                             float* __restrict__ out) {
    int lane = threadIdx.x;
    double rot = 0.0, trans = 0.0;
    const double* pf0 = ws + POSE_OFF + (size_t)NITER * NB * PSTRIDE;   // batch 0 final
    if (lane < NB) {
        // gt_rel = inv(P0) @ Pb
        const float* P0 = pose;
        const float* Pb = pose + lane * 16;
        double R0t[9];
        #pragma unroll
        for (int i = 0; i < 3; i++)
            #pragma unroll
            for (int j = 0; j < 3; j++) R0t[i*3+j] = (double)P0[j*4+i];
        double t0i[3];
        #pragma unroll
        for (int i = 0; i < 3; i++)
            t0i[i] = -(R0t[i*3+0]*P0[0*4+3] + R0t[i*3+1]*P0[1*4+3] + R0t[i*3+2]*P0[2*4+3]);
        double Rg[9], tg[3];
        #pragma unroll
        for (int i = 0; i < 3; i++) {
            #pragma unroll
            for (int j = 0; j < 3; j++)
                Rg[i*3+j] = R0t[i*3+0]*Pb[0*4+j] + R0t[i*3+1]*Pb[1*4+j] + R0t[i*3+2]*Pb[2*4+j];
            tg[i] = R0t[i*3+0]*Pb[0*4+3] + R0t[i*3+1]*Pb[1*4+3] + R0t[i*3+2]*Pb[2*4+3] + t0i[i];
        }
        // pred_rel = inv(T0) @ Tb  (all final poses already in ws)
        const double* pfb = ws + POSE_OFF + ((size_t)NITER * NB + lane) * PSTRIDE;
        double Rp0t[9];
        #pragma unroll
        for (int i = 0; i < 3; i++)
            #pragma unroll
            for (int j = 0; j < 3; j++) Rp0t[i*3+j] = pf0[j*3+i];
        double tp0i[3];
        #pragma unroll
        for (int i = 0; i < 3; i++)
            tp0i[i] = -(Rp0t[i*3+0]*pf0[9] + Rp0t[i*3+1]*pf0[10] + Rp0t[i*3+2]*pf0[11]);
        double Rr[9], trv[3];
        #pragma unroll
        for (int i = 0; i < 3; i++) {
            #pragma unroll
            for (int j = 0; j < 3; j++)
                Rr[i*3+j] = Rp0t[i*3+0]*pfb[0*3+j] + Rp0t[i*3+1]*pfb[1*3+j] + Rp0t[i*3+2]*pfb[2*3+j];
            trv[i] = Rp0t[i*3+0]*pfb[9] + Rp0t[i*3+1]*pfb[10] + Rp0t[i*3+2]*pfb[11] + tp0i[i];
        }
        double trace = 0.0;
        #pragma unroll
        for (int i = 0; i < 3; i++)
            trace += Rr[0*3+i]*Rg[0*3+i] + Rr[1*3+i]*Rg[1*3+i] + Rr[2*3+i]*Rg[2*3+i];
        double cosang = 0.5 * (trace - 1.0);
        cosang = fmin(fmax(cosang, -1.0 + 1e-7), 1.0 - 1e-7);
        rot = acos(cosang);
        double d0 = trv[0]-tg[0], d1 = trv[1]-tg[1], d2 = trv[2]-tg[2];
        trans = sqrt(d0*d0 + d1*d1 + d2*d2);
    }
    for (int off = 8; off > 0; off >>= 1) {
        rot   += __shfl_down(rot, off, 64);
        trans += __shfl_down(trans, off, 64);
    }
    if (lane == 0) {
        rot /= NB; trans /= NB;
        out[0] = (float)(rot + trans);
        out[1] = (float)rot;
        out[2] = (float)trans;
    }
}

extern "C" void kernel_launch(void* const* d_in, const int* in_sizes, int n_in,
                              void* d_out, int out_size, void* d_ws, size_t ws_size,
                              hipStream_t stream) {
    const float* x3d  = (const float*)d_in[0];
    const float* conf = (const float*)d_in[1];
    const float* Kmat = (const float*)d_in[2];
    const float* pose = (const float*)d_in[3];
    float* out = (float*)d_out;
    double* ws = (double*)d_ws;

    hipLaunchKernelGGL(init_k, dim3(1), dim3(TPB), 0, stream, ws);
    for (int it = 0; it < NITER; ++it) {
        hipLaunchKernelGGL(reduce_k, dim3(NBLK), dim3(TPB), 0, stream,
                           x3d, conf, Kmat, ws, it);
    }
    hipLaunchKernelGGL(loss_k, dim3(1), dim3(64), 0, stream, ws, pose, out);
}

// Round 17
// 85.591 us; speedup vs baseline: 1.3731x; 1.3731x over previous
//
#include <hip/hip_runtime.h>
#include <math.h>

#define NB 16
#define IMH 288
#define IMW 384
#define NPIX (IMH*IMW)
#define TPB 256
#define PPT 16
#define BPB (NPIX/(TPB*PPT))   // 27 blocks per batch
#define NBLK (NB*BPB)          // 432
#define NITER 5

// ws doubles layout: pose[2][NB][12] (R[9]+t[3], parity buffers) | acc[NITER][NB][27]
#define POSE_OFF 0
#define ACC_OFF (2*NB*12)
#define WS_DOUBLES (2*NB*12 + NITER*NB*27)

// f32 register-resident LM update (matches reference's f32 trajectory);
// t accumulates in f64 (state), everything else f32. Fully unrolled.
__device__ __forceinline__ void solve_updatef(const double* __restrict__ acc,
                                              const double* __restrict__ pin,
                                              float* __restrict__ Ro,
                                              double* __restrict__ to) {
    float A[6][6], rhs[6], inv[6];
    {
        int k = 0;
        #pragma unroll
        for (int f = 0; f < 6; f++) {
            #pragma unroll 6
            for (int g = f; g < 6; g++) {
                float v = (float)acc[k];
                A[f][g] = v; A[g][f] = v; k++;
            }
        }
    }
    #pragma unroll
    for (int f = 0; f < 6; f++) rhs[f] = -(float)acc[21 + f];

    float tr = A[0][0]+A[1][1]+A[2][2]+A[3][3]+A[4][4]+A[5][5];
    float damp = 1e-4f * tr * (1.0f/6.0f) + 1e-6f;
    #pragma unroll
    for (int f = 0; f < 6; f++) A[f][f] += damp;

    #pragma unroll
    for (int j = 0; j < 6; j++) {
        float s = A[j][j];
        #pragma unroll 6
        for (int m = 0; m < j; m++) s = fmaf(-A[j][m], A[j][m], s);
        float dd = __builtin_amdgcn_sqrtf(fmaxf(s, 1e-20f));
        A[j][j] = dd;
        inv[j] = __builtin_amdgcn_rcpf(dd);
        #pragma unroll 6
        for (int i = j + 1; i < 6; i++) {
            float s2 = A[i][j];
            #pragma unroll 6
            for (int m = 0; m < j; m++) s2 = fmaf(-A[i][m], A[j][m], s2);
            A[i][j] = s2 * inv[j];
        }
    }
    #pragma unroll
    for (int i = 0; i < 6; i++) {
        float s = rhs[i];
        #pragma unroll 6
        for (int m = 0; m < i; m++) s = fmaf(-A[i][m], rhs[m], s);
        rhs[i] = s * inv[i];
    }
    #pragma unroll
    for (int i = 5; i >= 0; i--) {
        float s = rhs[i];
        #pragma unroll 6
        for (int m = i + 1; m < 6; m++) s = fmaf(-A[m][i], rhs[m], s);
        rhs[i] = s * inv[i];
    }

    to[0] = pin[9]  + (double)rhs[0];
    to[1] = pin[10] + (double)rhs[1];
    to[2] = pin[11] + (double)rhs[2];

    float wx = rhs[3], wy = rhs[4], wz = rhs[5];
    float th = fmaxf(__builtin_amdgcn_sqrtf(fmaf(wx,wx,fmaf(wy,wy,wz*wz))), 1e-8f);
    float ith = __builtin_amdgcn_rcpf(th);
    float kx = wx*ith, ky = wy*ith, kz = wz*ith;
    float st, ctf;
    sincosf(th, &st, &ctf);
    float ct = 1.0f - ctf;
    float E[9];
    E[0] = 1.0f + ct*(kx*kx - 1.0f);
    E[1] = -st*kz + ct*kx*ky;
    E[2] =  st*ky + ct*kx*kz;
    E[3] =  st*kz + ct*ky*kx;
    E[4] = 1.0f + ct*(ky*ky - 1.0f);
    E[5] = -st*kx + ct*ky*kz;
    E[6] = -st*ky + ct*kz*kx;
    E[7] =  st*kx + ct*kz*ky;
    E[8] = 1.0f + ct*(kz*kz - 1.0f);

    float Rin[9];
    #pragma unroll
    for (int i = 0; i < 9; i++) Rin[i] = (float)pin[i];
    #pragma unroll
    for (int i = 0; i < 3; i++) {
        #pragma unroll
        for (int j = 0; j < 3; j++)
            Ro[i*3+j] = E[i*3+0]*Rin[0*3+j] + E[i*3+1]*Rin[1*3+j] + E[i*3+2]*Rin[2*3+j];
    }
}

__global__ void init_k(double* ws) {
    int i = threadIdx.x;
    for (int k = i; k < WS_DOUBLES; k += TPB) ws[k] = 0.0;
    __syncthreads();
    if (i < NB) {
        double* p = ws + POSE_OFF + i * 12;   // parity buffer 0 = identity
        p[0] = 1.0; p[4] = 1.0; p[8] = 1.0;
    }
}

__global__ __launch_bounds__(TPB) void reduce_k(const float* __restrict__ x3d,
                                                const float* __restrict__ conf,
                                                const float* __restrict__ Kmat,
                                                double* __restrict__ ws, int it) {
    const int b = blockIdx.x / BPB;
    const int chunk = blockIdx.x % BPB;
    const int tid = threadIdx.x;

    const int ft = chunk * TPB + tid;              // [0, 6912)
    const float4* P4 = reinterpret_cast<const float4*>(x3d + (size_t)b * NPIX * 3) + (size_t)ft * 12;
    const float4* W4 = reinterpret_cast<const float4*>(conf + (size_t)b * NPIX) + (size_t)ft * 4;

    __shared__ double lds[TPB / 64][27];

    // ---- per-wave redundant f32 pose solve: no barrier, no LDS broadcast ----
    float R[9], t[3];
    if (it == 0) {
        R[0]=1.f; R[1]=0.f; R[2]=0.f;
        R[3]=0.f; R[4]=1.f; R[5]=0.f;
        R[6]=0.f; R[7]=0.f; R[8]=1.f;
        t[0]=t[1]=t[2]=0.f;
    } else {
        float Rn[9]; double tn[3];
        solve_updatef(ws + ACC_OFF + ((size_t)(it-1) * NB + b) * 27,
                      ws + POSE_OFF + (size_t)((it-1) & 1) * NB * 12 + (size_t)b * 12,
                      Rn, tn);
        #pragma unroll
        for (int i = 0; i < 9; i++) R[i] = Rn[i];
        t[0] = (float)tn[0]; t[1] = (float)tn[1]; t[2] = (float)tn[2];
        if (chunk == 0 && tid == 0) {      // publish pose state for next dispatch
            double* pout = ws + POSE_OFF + (size_t)(it & 1) * NB * 12 + (size_t)b * 12;
            #pragma unroll
            for (int i = 0; i < 9; i++) pout[i] = (double)Rn[i];
            pout[9] = tn[0]; pout[10] = tn[1]; pout[11] = tn[2];
        }
    }

    const float fx = Kmat[b*9 + 0];
    const float fy = Kmat[b*9 + 4];
    const float cx = Kmat[b*9 + 2];
    const float cy = Kmat[b*9 + 5];
    const float delta = (float)(0.1 * sqrt(((double)(IMW*IMW - 1) + (double)(IMH*IMH - 1)) / 12.0));

    const int n0 = ft * PPT;
    const int v0 = n0 / IMW;                       // 16 points share one pixel row (384%16==0)
    const float cyv  = cy - (float)v0;
    const float cxu0 = cx - (float)(n0 - v0 * IMW);

    float facc[27];
    #pragma unroll
    for (int i = 0; i < 27; i++) facc[i] = 0.0f;

    // 4 groups of 4 points; per-group vector loads (compiler pipelines groups)
    #pragma unroll
    for (int gq = 0; gq < 4; ++gq) {
        const float4 va = P4[gq*3 + 0];
        const float4 vb = P4[gq*3 + 1];
        const float4 vc = P4[gq*3 + 2];
        const float4 vw = W4[gq];
        float ppx[4] = { va.x, va.w, vb.z, vc.y };
        float ppy[4] = { va.y, vb.x, vb.w, vc.z };
        float ppz[4] = { va.z, vb.y, vc.x, vc.w };
        float pw[4]  = { vw.x, vw.y, vw.z, vw.w };

        #pragma unroll
        for (int g = 0; g < 4; ++g) {
            float px = ppx[g], py = ppy[g], pz = ppz[g], w = pw[g];
            float u_off = cxu0 - (float)(gq * 4 + g);

            float Xx = fmaf(R[0], px, fmaf(R[1], py, fmaf(R[2], pz, t[0])));
            float Xy = fmaf(R[3], px, fmaf(R[4], py, fmaf(R[5], pz, t[1])));
            float Xz = fmaf(R[6], px, fmaf(R[7], py, fmaf(R[8], pz, t[2])));
            float z  = fmaxf(Xz, 0.01f);
            float iz = __builtin_amdgcn_rcpf(z);

            float Xxiz = Xx * iz, Xyiz = Xy * iz;
            float rx = fmaf(fx, Xxiz, u_off);
            float ry = fmaf(fy, Xyiz, cyv);

            float wrx = w * rx, wry = w * ry;
            float q  = fmaf(wrx, wrx, wry * wry);
            float rs = __builtin_amdgcn_rsqf(fmaxf(q, 1e-16f));
            float rob2 = fminf(1.0f, delta * rs);
            float sq = w * __builtin_amdgcn_sqrtf(rob2);

            float sqiz = sq * iz;
            float a  = fx * sqiz;
            float c  = fy * sqiz;
            float bb = -a * Xxiz;
            float d  = -c * Xyiz;

            float j0[6] = { a, 0.0f, bb,  bb*Xy,               fmaf(a, Xz, -bb*Xx), -a*Xy };
            float j1[6] = { 0.0f, c,  d,  fmaf(d, Xy, -c*Xz), -d*Xx,                 c*Xx };
            float rxs = sq * rx, rys = sq * ry;

            int k = 0;
            #pragma unroll
            for (int f = 0; f < 6; ++f) {
                #pragma unroll
                for (int gg = f; gg < 6; ++gg) {
                    facc[k] += j0[f]*j0[gg] + j1[f]*j1[gg];
                    k++;
                }
            }
            #pragma unroll
            for (int f = 0; f < 6; ++f)
                facc[21 + f] += j0[f]*rxs + j1[f]*rys;
        }
    }

    // f32 wave reduce (pairwise), f64 from wave partials on
    int lane = tid & 63;
    int wave = tid >> 6;
    #pragma unroll
    for (int i = 0; i < 27; i++) {
        float v = facc[i];
        for (int off = 32; off > 0; off >>= 1) v += __shfl_down(v, off, 64);
        if (lane == 0) lds[wave][i] = (double)v;
    }
    __syncthreads();

    double* acc = ws + ACC_OFF + ((size_t)it * NB + b) * 27;
    if (tid < 27) {
        double v = 0.0;
        #pragma unroll
        for (int wv = 0; wv < TPB/64; wv++) v += lds[wv][tid];
        atomicAdd(acc + tid, v);
    }
}

__global__ __launch_bounds__(64) void loss_k(const double* __restrict__ ws,
                                             const float* __restrict__ pose,
                                             float* __restrict__ out) {
    int lane = threadIdx.x;
    double Rp[9] = {1,0,0, 0,1,0, 0,0,1}, tp[3] = {0,0,0};
    if (lane < NB) {
        float Rn[9]; double tn[3];
        solve_updatef(ws + ACC_OFF + ((size_t)(NITER-1) * NB + lane) * 27,
                      ws + POSE_OFF + (size_t)((NITER-1) & 1) * NB * 12 + (size_t)lane * 12,
                      Rn, tn);
        #pragma unroll
        for (int i = 0; i < 9; i++) Rp[i] = (double)Rn[i];
        tp[0] = tn[0]; tp[1] = tn[1]; tp[2] = tn[2];
    }
    // broadcast batch-0 predicted pose to all lanes
    double Rp0[9], tp0v[3];
    #pragma unroll
    for (int i = 0; i < 9; i++) Rp0[i] = __shfl(Rp[i], 0, 64);
    #pragma unroll
    for (int i = 0; i < 3; i++) tp0v[i] = __shfl(tp[i], 0, 64);

    double rot = 0.0, trans = 0.0;
    if (lane < NB) {
        // gt_rel = inv(P0) @ Pb
        const float* P0 = pose;
        const float* Pb = pose + lane * 16;
        double R0t[9];
        #pragma unroll
        for (int i = 0; i < 3; i++)
            #pragma unroll
            for (int j = 0; j < 3; j++) R0t[i*3+j] = (double)P0[j*4+i];
        double t0i[3];
        #pragma unroll
        for (int i = 0; i < 3; i++)
            t0i[i] = -(R0t[i*3+0]*P0[0*4+3] + R0t[i*3+1]*P0[1*4+3] + R0t[i*3+2]*P0[2*4+3]);
        double Rg[9], tg[3];
        #pragma unroll
        for (int i = 0; i < 3; i++) {
            #pragma unroll
            for (int j = 0; j < 3; j++)
                Rg[i*3+j] = R0t[i*3+0]*Pb[0*4+j] + R0t[i*3+1]*Pb[1*4+j] + R0t[i*3+2]*Pb[2*4+j];
            tg[i] = R0t[i*3+0]*Pb[0*4+3] + R0t[i*3+1]*Pb[1*4+3] + R0t[i*3+2]*Pb[2*4+3] + t0i[i];
        }
        // pred_rel = inv(T0) @ Tb
        double Rp0t[9];
        #pragma unroll
        for (int i = 0; i < 3; i++)
            #pragma unroll
            for (int j = 0; j < 3; j++) Rp0t[i*3+j] = Rp0[j*3+i];
        double tp0i[3];
        #pragma unroll
        for (int i = 0; i < 3; i++)
            tp0i[i] = -(Rp0t[i*3+0]*tp0v[0] + Rp0t[i*3+1]*tp0v[1] + Rp0t[i*3+2]*tp0v[2]);
        double Rr[9], tr[3];
        #pragma unroll
        for (int i = 0; i < 3; i++) {
            #pragma unroll
            for (int j = 0; j < 3; j++)
                Rr[i*3+j] = Rp0t[i*3+0]*Rp[0*3+j] + Rp0t[i*3+1]*Rp[1*3+j] + Rp0t[i*3+2]*Rp[2*3+j];
            tr[i] = Rp0t[i*3+0]*tp[0] + Rp0t[i*3+1]*tp[1] + Rp0t[i*3+2]*tp[2] + tp0i[i];
        }
        double trace = 0.0;
        #pragma unroll
        for (int i = 0; i < 3; i++)
            trace += Rr[0*3+i]*Rg[0*3+i] + Rr[1*3+i]*Rg[1*3+i] + Rr[2*3+i]*Rg[2*3+i];
        double cosang = 0.5 * (trace - 1.0);
        cosang = fmin(fmax(cosang, -1.0 + 1e-7), 1.0 - 1e-7);
        rot = acos(cosang);
        double d0 = tr[0]-tg[0], d1 = tr[1]-tg[1], d2 = tr[2]-tg[2];
        trans = sqrt(d0*d0 + d1*d1 + d2*d2);
    }
    for (int off = 8; off > 0; off >>= 1) {
        rot   += __shfl_down(rot, off, 64);
        trans += __shfl_down(trans, off, 64);
    }
    if (lane == 0) {
        rot /= NB; trans /= NB;
        out[0] = (float)(rot + trans);
        out[1] = (float)rot;
        out[2] = (float)trans;
    }
}

extern "C" void kernel_launch(void* const* d_in, const int* in_sizes, int n_in,
                              void* d_out, int out_size, void* d_ws, size_t ws_size,
                              hipStream_t stream) {
    const float* x3d  = (const float*)d_in[0];
    const float* conf = (const float*)d_in[1];
    const float* Kmat = (const float*)d_in[2];
    const float* pose = (const float*)d_in[3];
    float* out = (float*)d_out;
    double* ws = (double*)d_ws;

    hipLaunchKernelGGL(init_k, dim3(1), dim3(TPB), 0, stream, ws);
    for (int it = 0; it < NITER; ++it) {
        hipLaunchKernelGGL(reduce_k, dim3(NBLK), dim3(TPB), 0, stream,
                           x3d, conf, Kmat, ws, it);
    }
    hipLaunchKernelGGL(loss_k, dim3(1), dim3(64), 0, stream, ws, pose, out);
}